// Round 1
// baseline (41330.179 us; speedup 1.0000x reference)
//
#include <hip/hip_runtime.h>

#define B_   32
#define T_   2048
#define F_   512
#define NWG  32
#define LDSPAD 520   // ushorts per LDS row (512 + 8) -> 1040B rows, 16B aligned

typedef float  float4v __attribute__((ext_vector_type(4)));
typedef short  short8v __attribute__((ext_vector_type(8)));
typedef unsigned short ushort_t;

__device__ __forceinline__ ushort_t f2bf(float f) {
  union { float f; unsigned u; } v; v.f = f;
  unsigned r = (v.u + 0x7FFFu + ((v.u >> 16) & 1u)) >> 16;  // RTN-ish
  return (ushort_t)r;
}

__device__ __forceinline__ float sigm(float x) {
  x = fmaxf(x, -30.f);
  return 1.f / (1.f + __expf(-x));
}
__device__ __forceinline__ float tanh_(float x) {
  x = fminf(fmaxf(x, -15.f), 15.f);
  float e = __expf(2.f * x);
  return (e - 1.f) / (e + 1.f);
}

// W1[n,k] = sum_j W_hh[n,j] * W_hs[j,k]   (fold: h2 @ W_hh^T == h_new @ W1^T)
__global__ void k_prep_w1(const float* __restrict__ Whh, const float* __restrict__ Whs,
                          ushort_t* __restrict__ w1) {
  int idx = blockIdx.x * 256 + threadIdx.x;
  if (idx >= 2048 * 512) return;
  int n = idx >> 9, k = idx & 511;
  const float* whr = Whh + (size_t)n * 512;
  const float* wsk = Whs + k;
  float s = 0.f;
  #pragma unroll 8
  for (int j = 0; j < 512; ++j) s += whr[j] * wsk[(size_t)j * 512];
  w1[idx] = f2bf(s);
}

__global__ void k_prep_misc(const float* __restrict__ Wih, const float* __restrict__ Wcs,
                            const float* __restrict__ Whs, const float* __restrict__ bih,
                            const float* __restrict__ bhh,
                            ushort_t* __restrict__ wih_bf, ushort_t* __restrict__ wcs_bf,
                            ushort_t* __restrict__ whs_bf, float* __restrict__ bias,
                            ushort_t* __restrict__ HN, ushort_t* __restrict__ CN,
                            int* __restrict__ flags) {
  const int total = 1048576 + 262144 + 262144 + 2048 + 16384 + 16384 + NWG;
  for (int i = blockIdx.x * blockDim.x + threadIdx.x; i < total; i += gridDim.x * blockDim.x) {
    int r = i;
    if (r < 1048576) { wih_bf[r] = f2bf(Wih[r]); continue; }
    r -= 1048576;
    if (r < 262144)  { wcs_bf[r] = f2bf(Wcs[r]); continue; }
    r -= 262144;
    if (r < 262144)  { whs_bf[r] = f2bf(Whs[r]); continue; }
    r -= 262144;
    if (r < 2048)    { bias[r] = bih[r] + bhh[r]; continue; }
    r -= 2048;
    if (r < 16384)   { HN[3 * 16384 + r] = 0; continue; }   // zero ring slot 3 (state t=-1)
    r -= 16384;
    if (r < 16384)   { CN[3 * 16384 + r] = 0; continue; }
    r -= 16384;
    flags[r] = 0;
  }
}

// Persistent recurrent kernel. One WG per 16-feature block (fb). Per step t:
//   gates_t = x_t@Wih^T + bias + hn_{t-1}@W1^T ; c_in = cn_{t-1}@Wcs^T ; h2_{t-1} = hn_{t-1}@Whs^T
//   cn_t = sig(f)*c_in + sig(i)*tanh(g) ; hn_t = sig(o)*tanh(cn_t)
//   out[t-1] = x_{t-1} + tanh(tanh(tanh(h2+c2) + x_{t-1}))
__global__ __launch_bounds__(256) void k_lstm(
    const float* __restrict__ X,
    const ushort_t* __restrict__ w1, const ushort_t* __restrict__ wih,
    const ushort_t* __restrict__ wcs, const ushort_t* __restrict__ whs,
    const float* __restrict__ bias,
    ushort_t* __restrict__ HN, ushort_t* __restrict__ CN,
    int* __restrict__ flags, float* __restrict__ out)
{
  const int fb   = blockIdx.x;      // 0..31 feature block
  const int tid  = threadIdx.x;
  const int wid  = tid >> 6;
  const int lane = tid & 63;
  const int mh   = wid & 1;         // batch half (rows 0-15 / 16-31)
  const int ar   = lane & 15;
  const int ko   = (lane >> 4) << 3;

  __shared__ ushort_t s_hn[32 * LDSPAD];
  __shared__ float s_tiles[12][16][16];
  __shared__ float s_bias[4][16];

  if (tid < 64) s_bias[tid >> 4][tid & 15] = bias[(tid >> 4) * 512 + fb * 16 + (tid & 15)];

  // wave -> 3 tiles: t0=wid (gate i/f), t1=wid+4 (gate g/o), t2=wid+8 (c2 for waves 0/1, h2 for 2/3)
  // tile id = gate_type*2 + mh for ids 0..7 ; 8+mh = c2 ; 10+mh = h2
  const int gtype0 = (wid >> 1);
  const int gtype1 = 2 + (wid >> 1);
  const ushort_t* bp0 = w1  + ((size_t)(gtype0 * 512 + fb * 16 + ar)) * 512 + ko;
  const ushort_t* bx0 = wih + ((size_t)(gtype0 * 512 + fb * 16 + ar)) * 512 + ko;
  const ushort_t* bp1 = w1  + ((size_t)(gtype1 * 512 + fb * 16 + ar)) * 512 + ko;
  const ushort_t* bx1 = wih + ((size_t)(gtype1 * 512 + fb * 16 + ar)) * 512 + ko;
  const ushort_t* bp2 = ((wid < 2) ? wcs : whs) + ((size_t)(fb * 16 + ar)) * 512 + ko;

  const int t0 = wid, t1 = wid + 4, t2 = wid + 8;
  const int arow_x = mh * 16 + ar;  // global batch row for this lane's A fragments

  for (int t = 0; t <= T_; ++t) {
    float4v acc0 = {0.f, 0.f, 0.f, 0.f};
    float4v acc1 = acc0, acc2 = acc0;

    // ---- x-pass (state independent, issued BEFORE the barrier poll) ----
    if (t < T_) {
      const float* xrow = X + (size_t)arow_x * (T_ * F_) + (size_t)t * F_ + ko;
      #pragma unroll 4
      for (int kk = 0; kk < 16; ++kk) {
        const float* p = xrow + kk * 32;
        float4v xa = *(const float4v*)(p);
        float4v xb = *(const float4v*)(p + 4);
        short8v a;
        a[0] = (short)f2bf(xa[0]); a[1] = (short)f2bf(xa[1]);
        a[2] = (short)f2bf(xa[2]); a[3] = (short)f2bf(xa[3]);
        a[4] = (short)f2bf(xb[0]); a[5] = (short)f2bf(xb[1]);
        a[6] = (short)f2bf(xb[2]); a[7] = (short)f2bf(xb[3]);
        short8v b0 = *(const short8v*)(bx0 + (size_t)kk * 32);
        short8v b1 = *(const short8v*)(bx1 + (size_t)kk * 32);
        acc0 = __builtin_amdgcn_mfma_f32_16x16x32_bf16(a, b0, acc0, 0, 0, 0);
        acc1 = __builtin_amdgcn_mfma_f32_16x16x32_bf16(a, b1, acc1, 0, 0, 0);
      }
    }

    // ---- wait until all WGs published state t-1 ----
    if (t > 0) {
      if (wid == 0) {
        while (true) {
          int v = (lane < NWG)
                ? __hip_atomic_load(flags + lane, __ATOMIC_RELAXED, __HIP_MEMORY_SCOPE_AGENT)
                : t;
          if (__all(v >= t)) break;
          __builtin_amdgcn_s_sleep(8);
        }
      }
      __syncthreads();
    }

    // ---- stage hn(t-1) into LDS via coherent 8B loads ----
    {
      const ushort_t* hsrc = HN + (size_t)((t + 3) & 3) * (32 * 512);
      for (int c = tid; c < 4096; c += 256) {
        int r = c >> 7, q = c & 127;
        unsigned long long v = __hip_atomic_load(
            (unsigned long long*)(hsrc + r * 512 + q * 4),
            __ATOMIC_RELAXED, __HIP_MEMORY_SCOPE_AGENT);
        *(unsigned long long*)&s_hn[r * LDSPAD + q * 4] = v;
      }
    }
    __syncthreads();

    // ---- state passes: W1 (gates), Wcs (c2) / Whs (h2) ----
    {
      const ushort_t* cnrow = CN + (size_t)((t + 3) & 3) * (32 * 512)
                            + (size_t)arow_x * 512 + ko;
      const int arow = (mh * 16 + ar) * LDSPAD;
      #pragma unroll 4
      for (int kk = 0; kk < 16; ++kk) {
        short8v ah = *(const short8v*)&s_hn[arow + kk * 32 + ko];
        short8v b0 = *(const short8v*)(bp0 + (size_t)kk * 32);
        short8v b1 = *(const short8v*)(bp1 + (size_t)kk * 32);
        acc0 = __builtin_amdgcn_mfma_f32_16x16x32_bf16(ah, b0, acc0, 0, 0, 0);
        acc1 = __builtin_amdgcn_mfma_f32_16x16x32_bf16(ah, b1, acc1, 0, 0, 0);
        short8v a2;
        if (wid < 2) {
          unsigned long long lo = __hip_atomic_load(
              (unsigned long long*)(cnrow + kk * 32),
              __ATOMIC_RELAXED, __HIP_MEMORY_SCOPE_AGENT);
          unsigned long long hi = __hip_atomic_load(
              (unsigned long long*)(cnrow + kk * 32 + 4),
              __ATOMIC_RELAXED, __HIP_MEMORY_SCOPE_AGENT);
          union { unsigned long long q[2]; short8v s; } u;
          u.q[0] = lo; u.q[1] = hi;
          a2 = u.s;
        } else {
          a2 = ah;
        }
        short8v b2 = *(const short8v*)(bp2 + (size_t)kk * 32);
        acc2 = __builtin_amdgcn_mfma_f32_16x16x32_bf16(a2, b2, acc2, 0, 0, 0);
      }
    }

    // ---- C tiles -> LDS ----
    {
      const int rb = (lane >> 4) << 2, cc = lane & 15;
      #pragma unroll
      for (int r = 0; r < 4; ++r) {
        s_tiles[t0][rb + r][cc] = acc0[r];
        s_tiles[t1][rb + r][cc] = acc1[r];
        s_tiles[t2][rb + r][cc] = acc2[r];
      }
    }
    __syncthreads();

    // ---- elementwise cell update + coherent state store ----
    if (t < T_ && tid < 128) {
      const int b = tid >> 2, jq = (tid & 3) << 2;
      const int mh_ = b >> 4, br = b & 15;
      unsigned long long hq = 0, cq = 0;
      #pragma unroll
      for (int u = 0; u < 4; ++u) {
        int j = jq + u;
        float iv  = s_tiles[0 + mh_][br][j] + s_bias[0][j];
        float fv  = s_tiles[2 + mh_][br][j] + s_bias[1][j];
        float gv  = s_tiles[4 + mh_][br][j] + s_bias[2][j];
        float ov  = s_tiles[6 + mh_][br][j] + s_bias[3][j];
        float c2p = s_tiles[8 + mh_][br][j];
        float cnv = sigm(fv) * c2p + sigm(iv) * tanh_(gv);
        float hnv = sigm(ov) * tanh_(cnv);
        hq |= ((unsigned long long)f2bf(hnv)) << (16 * u);
        cq |= ((unsigned long long)f2bf(cnv)) << (16 * u);
      }
      size_t uso = (size_t)(t & 3) * (32 * 512) + (size_t)b * 512 + fb * 16 + jq;
      __hip_atomic_store((unsigned long long*)(HN + uso), hq,
                         __ATOMIC_RELAXED, __HIP_MEMORY_SCOPE_AGENT);
      __hip_atomic_store((unsigned long long*)(CN + uso), cq,
                         __ATOMIC_RELAXED, __HIP_MEMORY_SCOPE_AGENT);
    }
    __syncthreads();   // drains the agent-scope stores (vmcnt(0)) before the flag
    if (t < T_ && tid == 0)
      __hip_atomic_store(flags + fb, t + 1, __ATOMIC_RELAXED, __HIP_MEMORY_SCOPE_AGENT);

    // ---- output for step t-1 (off the critical path, after signaling) ----
    if (t > 0) {
      for (int it = tid; it < 512; it += 256) {
        const int b = it >> 4, j = it & 15;
        const int mh_ = b >> 4, br = b & 15;
        float c2p = s_tiles[8 + mh_][br][j];
        float h2p = s_tiles[10 + mh_][br][j];
        float att = tanh_(h2p + c2p);
        size_t xoff = (size_t)b * (T_ * F_) + (size_t)(t - 1) * F_ + fb * 16 + j;
        float xo = X[xoff];
        float o1 = tanh_(att + xo);
        out[xoff] = xo + tanh_(o1);
      }
    }
  }
}

extern "C" void kernel_launch(void* const* d_in, const int* in_sizes, int n_in,
                              void* d_out, int out_size, void* d_ws, size_t ws_size,
                              hipStream_t stream) {
  const float* X   = (const float*)d_in[0];
  const float* Wih = (const float*)d_in[1];
  const float* Whh = (const float*)d_in[2];
  const float* bih = (const float*)d_in[3];
  const float* bhh = (const float*)d_in[4];
  const float* Whs = (const float*)d_in[5];
  const float* Wcs = (const float*)d_in[6];

  char* ws = (char*)d_ws;
  ushort_t* w1_bf  = (ushort_t*)(ws + 0);        // 2,097,152 B
  ushort_t* wih_bf = (ushort_t*)(ws + 2097152);  // 2,097,152 B
  ushort_t* wcs_bf = (ushort_t*)(ws + 4194304);  //   524,288 B
  ushort_t* whs_bf = (ushort_t*)(ws + 4718592);  //   524,288 B
  float*    bias   = (float*)   (ws + 5242880);  //     8,192 B
  ushort_t* HN     = (ushort_t*)(ws + 5251072);  //   131,072 B (4-slot ring)
  ushort_t* CN     = (ushort_t*)(ws + 5382144);  //   131,072 B
  int*      flags  = (int*)     (ws + 5513216);  //       128 B
  if (ws_size < (size_t)5513344) return;

  k_prep_w1<<<4096, 256, 0, stream>>>(Whh, Whs, w1_bf);
  k_prep_misc<<<2048, 256, 0, stream>>>(Wih, Wcs, Whs, bih, bhh,
                                        wih_bf, wcs_bf, whs_bf, bias, HN, CN, flags);
  k_lstm<<<NWG, 256, 0, stream>>>(X, w1_bf, wih_bf, wcs_bf, whs_bf, bias,
                                  HN, CN, flags, (float*)d_out);
}

// Round 2
// 27697.699 us; speedup vs baseline: 1.4922x; 1.4922x over previous
//
#include <hip/hip_runtime.h>

#define T_   2048
#define NWG  32
#define WP   520   // padded LDS pitch in ushorts (1040B rows -> 4-bank stagger, 16B aligned)

typedef float  float4v __attribute__((ext_vector_type(4)));
typedef float  float2v __attribute__((ext_vector_type(2)));
typedef short  short8v __attribute__((ext_vector_type(8)));
typedef unsigned short ushort_t;

__device__ __forceinline__ ushort_t f2bf(float f) {
  union { float f; unsigned u; } v; v.f = f;
  unsigned r = (v.u + 0x7FFFu + ((v.u >> 16) & 1u)) >> 16;  // RTN
  return (ushort_t)r;
}
__device__ __forceinline__ float sigm(float x) {
  x = fmaxf(x, -30.f);
  return __fdividef(1.f, 1.f + __expf(-x));
}
__device__ __forceinline__ float tanh_(float x) {
  x = fminf(fmaxf(x, -15.f), 15.f);
  float e = __expf(2.f * x);
  return (e - 1.f) * __fdividef(1.f, e + 1.f);
}

// W1[n,k] = sum_j W_hh[n,j] * W_hs[j,k]   (fold: h2 @ W_hh^T == h_new @ W1^T)
__global__ void k_prep_w1(const float* __restrict__ Whh, const float* __restrict__ Whs,
                          ushort_t* __restrict__ w1) {
  int idx = blockIdx.x * 256 + threadIdx.x;
  if (idx >= 2048 * 512) return;
  int n = idx >> 9, k = idx & 511;
  const float* whr = Whh + (size_t)n * 512;
  const float* wsk = Whs + k;
  float s = 0.f;
  #pragma unroll 8
  for (int j = 0; j < 512; ++j) s += whr[j] * wsk[(size_t)j * 512];
  w1[idx] = f2bf(s);
}

__global__ void k_prep_misc(const float* __restrict__ Wih, const float* __restrict__ Wcs,
                            const float* __restrict__ Whs, const float* __restrict__ bih,
                            const float* __restrict__ bhh,
                            ushort_t* __restrict__ wih_bf, ushort_t* __restrict__ wcs_bf,
                            ushort_t* __restrict__ whs_bf, float* __restrict__ bias,
                            ushort_t* __restrict__ HN, ushort_t* __restrict__ CN,
                            int* __restrict__ flags) {
  const int total = 1048576 + 262144 + 262144 + 2048 + 16384 + 16384 + NWG;
  for (int i = blockIdx.x * blockDim.x + threadIdx.x; i < total; i += gridDim.x * blockDim.x) {
    int r = i;
    if (r < 1048576) { wih_bf[r] = f2bf(Wih[r]); continue; }
    r -= 1048576;
    if (r < 262144)  { wcs_bf[r] = f2bf(Wcs[r]); continue; }
    r -= 262144;
    if (r < 262144)  { whs_bf[r] = f2bf(Whs[r]); continue; }
    r -= 262144;
    if (r < 2048)    { bias[r] = bih[r] + bhh[r]; continue; }
    r -= 2048;
    if (r < 16384)   { HN[3 * 16384 + r] = 0; continue; }   // zero ring slot 3 (state t=-1)
    r -= 16384;
    if (r < 16384)   { CN[3 * 16384 + r] = 0; continue; }
    r -= 16384;
    flags[r] = 0;
  }
}

// Persistent recurrent kernel, one WG per 16-feature block (fb).
// Carry is (hn, cn); per step t:
//   gates = x_t@Wih^T + bias + hn@W1^T ; c2 = cn@Wcs^T ; h2 = hn@Whs^T
//   cn' = sig(f)*c2 + sig(i)*tanh(g) ; hn' = sig(o)*tanh(cn')
//   out[t-1] = x_{t-1} + tanh(tanh(tanh(h2+c2) + x_{t-1}))
__global__ __launch_bounds__(256, 1) void k_lstm(
    const float* __restrict__ X,
    const ushort_t* __restrict__ w1, const ushort_t* __restrict__ wih,
    const ushort_t* __restrict__ wcs, const ushort_t* __restrict__ whs,
    const float* __restrict__ bias,
    ushort_t* __restrict__ HN, ushort_t* __restrict__ CN,
    int* __restrict__ flags, float* __restrict__ out)
{
  const int fb   = blockIdx.x;
  const int tid  = threadIdx.x;
  const int wid  = tid >> 6;
  const int lane = tid & 63;
  const int mh   = wid & 1;          // batch half
  const int ar   = lane & 15;
  const int ko   = (lane >> 4) << 3;

  __shared__ ushort_t s_w1[64 * WP];   // rows: gate g (i,f,g,o) * 16 + r
  __shared__ ushort_t s_w2[32 * WP];   // rows 0-15: wcs slice, 16-31: whs slice
  __shared__ float s_tiles[12][16][16];

  // ---- one-time: stage weight slices into LDS ----
  for (int i = tid; i < 4096; i += 256) {            // w1: 64 rows x 64 16B-chunks
    int r = i >> 6, c = i & 63;
    int g = r >> 4, rr = r & 15;
    *(short8v*)&s_w1[r * WP + c * 8] =
        *(const short8v*)&w1[((size_t)(g * 512 + fb * 16 + rr)) * 512 + c * 8];
  }
  for (int i = tid; i < 2048; i += 256) {            // w2: 32 rows x 64 chunks
    int r = i >> 6, c = i & 63;
    const ushort_t* src = (r < 16) ? (wcs + ((size_t)(fb * 16 + r)) * 512)
                                   : (whs + ((size_t)(fb * 16 + r - 16)) * 512);
    *(short8v*)&s_w2[r * WP + c * 8] = *(const short8v*)&src[c * 8];
  }

  // ---- per-thread elementwise mapping + bias in registers ----
  const int eb  = tid >> 3;          // batch row 0..31
  const int ejp = (tid & 7) * 2;     // column pair within the 16-col block
  const int emh = eb >> 4, ebr = eb & 15;
  float bI[2], bF[2], bG[2], bO[2];
  #pragma unroll
  for (int u = 0; u < 2; ++u) {
    bI[u] = bias[0 * 512 + fb * 16 + ejp + u];
    bF[u] = bias[1 * 512 + fb * 16 + ejp + u];
    bG[u] = bias[2 * 512 + fb * 16 + ejp + u];
    bO[u] = bias[3 * 512 + fb * 16 + ejp + u];
  }

  const int gtype0 = wid >> 1;            // i or f
  const int gtype1 = 2 + (wid >> 1);      // g or o
  const ushort_t* bx0 = wih + ((size_t)(gtype0 * 512 + fb * 16 + ar)) * 512 + ko;
  const ushort_t* bx1 = wih + ((size_t)(gtype1 * 512 + fb * 16 + ar)) * 512 + ko;
  const int w1r0 = (gtype0 * 16 + ar) * WP + ko;
  const int w1r1 = (gtype1 * 16 + ar) * WP + ko;
  const int w2r  = ((wid < 2 ? ar : 16 + ar)) * WP + ko;
  const int arow_x = mh * 16 + ar;
  const int t0 = wid, t1 = wid + 4, t2 = wid + 8;

  __syncthreads();

  for (int t = 0; t <= T_; ++t) {
    float4v acc0 = {0.f, 0.f, 0.f, 0.f};
    float4v acc1 = acc0, acc2 = acc0;

    // ---- x-pass (state independent) ----
    if (t < T_) {
      const float* xrow = X + (size_t)arow_x * (T_ * 512) + (size_t)t * 512 + ko;
      #pragma unroll 4
      for (int kk = 0; kk < 16; ++kk) {
        const float* p = xrow + kk * 32;
        float4v xa = *(const float4v*)(p);
        float4v xb = *(const float4v*)(p + 4);
        short8v a;
        a[0] = (short)f2bf(xa[0]); a[1] = (short)f2bf(xa[1]);
        a[2] = (short)f2bf(xa[2]); a[3] = (short)f2bf(xa[3]);
        a[4] = (short)f2bf(xb[0]); a[5] = (short)f2bf(xb[1]);
        a[6] = (short)f2bf(xb[2]); a[7] = (short)f2bf(xb[3]);
        short8v b0 = *(const short8v*)(bx0 + (size_t)kk * 32);
        short8v b1 = *(const short8v*)(bx1 + (size_t)kk * 32);
        acc0 = __builtin_amdgcn_mfma_f32_16x16x32_bf16(a, b0, acc0, 0, 0, 0);
        acc1 = __builtin_amdgcn_mfma_f32_16x16x32_bf16(a, b1, acc1, 0, 0, 0);
      }
    }

    // ---- poll (all waves, busy) ----
    if (t > 0) {
      while (true) {
        int v = (lane < NWG)
              ? __hip_atomic_load(flags + lane, __ATOMIC_RELAXED, __HIP_MEMORY_SCOPE_AGENT)
              : t;
        if (__all(v >= t)) break;
      }
    }

    // ---- prefetch output-pass X (consumed at end of iteration) ----
    float2v xo2 = {0.f, 0.f};
    if (t > 0)
      xo2 = *(const float2v*)&X[(size_t)eb * (T_ * 512) + (size_t)(t - 1) * 512 + fb * 16 + ejp];

    // ---- state A-fragments -> registers (bulk, fully unrolled, pipelined) ----
    const int rs = (t + 3) & 3;
    const ushort_t* hb = HN + (size_t)rs * (32 * 512) + (size_t)arow_x * 512 + ko;
    short8v hfrag[16];
    #pragma unroll
    for (int kk = 0; kk < 16; ++kk) {
      unsigned long long lo = __hip_atomic_load(
          (unsigned long long*)(hb + kk * 32), __ATOMIC_RELAXED, __HIP_MEMORY_SCOPE_AGENT);
      unsigned long long hi = __hip_atomic_load(
          (unsigned long long*)(hb + kk * 32 + 4), __ATOMIC_RELAXED, __HIP_MEMORY_SCOPE_AGENT);
      union { unsigned long long q[2]; short8v s; } u; u.q[0] = lo; u.q[1] = hi;
      hfrag[kk] = u.s;
    }
    short8v cfrag[16];
    if (wid < 2) {
      const ushort_t* cb = CN + (size_t)rs * (32 * 512) + (size_t)arow_x * 512 + ko;
      #pragma unroll
      for (int kk = 0; kk < 16; ++kk) {
        unsigned long long lo = __hip_atomic_load(
            (unsigned long long*)(cb + kk * 32), __ATOMIC_RELAXED, __HIP_MEMORY_SCOPE_AGENT);
        unsigned long long hi = __hip_atomic_load(
            (unsigned long long*)(cb + kk * 32 + 4), __ATOMIC_RELAXED, __HIP_MEMORY_SCOPE_AGENT);
        union { unsigned long long q[2]; short8v s; } u; u.q[0] = lo; u.q[1] = hi;
        cfrag[kk] = u.s;
      }
    }

    // ---- state MFMA (pure LDS + registers) ----
    #pragma unroll
    for (int kk = 0; kk < 16; ++kk) {
      short8v b0 = *(const short8v*)&s_w1[w1r0 + kk * 32];
      short8v b1 = *(const short8v*)&s_w1[w1r1 + kk * 32];
      short8v b2 = *(const short8v*)&s_w2[w2r + kk * 32];
      acc0 = __builtin_amdgcn_mfma_f32_16x16x32_bf16(hfrag[kk], b0, acc0, 0, 0, 0);
      acc1 = __builtin_amdgcn_mfma_f32_16x16x32_bf16(hfrag[kk], b1, acc1, 0, 0, 0);
      short8v a2 = (wid < 2) ? cfrag[kk] : hfrag[kk];
      acc2 = __builtin_amdgcn_mfma_f32_16x16x32_bf16(a2, b2, acc2, 0, 0, 0);
    }

    __syncthreads();   // barrier1: previous iteration's output-readers are done with s_tiles

    {
      const int rb = (lane >> 4) << 2, cc = lane & 15;
      #pragma unroll
      for (int r = 0; r < 4; ++r) {
        s_tiles[t0][rb + r][cc] = acc0[r];
        s_tiles[t1][rb + r][cc] = acc1[r];
        s_tiles[t2][rb + r][cc] = acc2[r];
      }
    }
    __syncthreads();   // barrier2: tiles visible

    // ---- elementwise cell update + state store (all 256 threads, 2 cols each) ----
    if (t < T_) {
      unsigned hpk = 0, cpk = 0;
      #pragma unroll
      for (int u = 0; u < 2; ++u) {
        int j = ejp + u;
        float iv  = s_tiles[0 + emh][ebr][j] + bI[u];
        float fv  = s_tiles[2 + emh][ebr][j] + bF[u];
        float gv  = s_tiles[4 + emh][ebr][j] + bG[u];
        float ov  = s_tiles[6 + emh][ebr][j] + bO[u];
        float c2p = s_tiles[8 + emh][ebr][j];
        float cnv = sigm(fv) * c2p + sigm(iv) * tanh_(gv);
        float hnv = sigm(ov) * tanh_(cnv);
        hpk |= ((unsigned)f2bf(hnv)) << (16 * u);
        cpk |= ((unsigned)f2bf(cnv)) << (16 * u);
      }
      size_t uso = (size_t)(t & 3) * (32 * 512) + (size_t)eb * 512 + fb * 16 + ejp;
      __hip_atomic_store((unsigned*)(HN + uso), hpk,
                         __ATOMIC_RELAXED, __HIP_MEMORY_SCOPE_AGENT);
      __hip_atomic_store((unsigned*)(CN + uso), cpk,
                         __ATOMIC_RELAXED, __HIP_MEMORY_SCOPE_AGENT);
    }
    __syncthreads();   // barrier3: drains the agent-scope stores (vmcnt(0)) before flag
    if (t < T_ && tid == 0)
      __hip_atomic_store(flags + fb, t + 1, __ATOMIC_RELAXED, __HIP_MEMORY_SCOPE_AGENT);

    // ---- output for step t-1 (after signaling; uses this iteration's tiles) ----
    if (t > 0) {
      float ov2[2];
      #pragma unroll
      for (int u = 0; u < 2; ++u) {
        int j = ejp + u;
        float c2p = s_tiles[8 + emh][ebr][j];
        float h2p = s_tiles[10 + emh][ebr][j];
        float att = tanh_(h2p + c2p);
        float xo  = (u ? xo2[1] : xo2[0]);
        float o1  = tanh_(att + xo);
        ov2[u] = xo + tanh_(o1);
      }
      float2v o2; o2[0] = ov2[0]; o2[1] = ov2[1];
      *(float2v*)&out[(size_t)eb * (T_ * 512) + (size_t)(t - 1) * 512 + fb * 16 + ejp] = o2;
    }
  }
}

extern "C" void kernel_launch(void* const* d_in, const int* in_sizes, int n_in,
                              void* d_out, int out_size, void* d_ws, size_t ws_size,
                              hipStream_t stream) {
  const float* X   = (const float*)d_in[0];
  const float* Wih = (const float*)d_in[1];
  const float* Whh = (const float*)d_in[2];
  const float* bih = (const float*)d_in[3];
  const float* bhh = (const float*)d_in[4];
  const float* Whs = (const float*)d_in[5];
  const float* Wcs = (const float*)d_in[6];

  char* ws = (char*)d_ws;
  ushort_t* w1_bf  = (ushort_t*)(ws + 0);        // 2,097,152 B
  ushort_t* wih_bf = (ushort_t*)(ws + 2097152);  // 2,097,152 B
  ushort_t* wcs_bf = (ushort_t*)(ws + 4194304);  //   524,288 B
  ushort_t* whs_bf = (ushort_t*)(ws + 4718592);  //   524,288 B
  float*    bias   = (float*)   (ws + 5242880);  //     8,192 B
  ushort_t* HN     = (ushort_t*)(ws + 5251072);  //   131,072 B (4-slot ring)
  ushort_t* CN     = (ushort_t*)(ws + 5382144);  //   131,072 B
  int*      flags  = (int*)     (ws + 5513216);  //       128 B
  if (ws_size < (size_t)5513344) return;

  k_prep_w1<<<4096, 256, 0, stream>>>(Whh, Whs, w1_bf);
  k_prep_misc<<<2048, 256, 0, stream>>>(Wih, Wcs, Whs, bih, bhh,
                                        wih_bf, wcs_bf, whs_bf, bias, HN, CN, flags);
  k_lstm<<<NWG, 256, 0, stream>>>(X, w1_bf, wih_bf, wcs_bf, whs_bf, bias,
                                  HN, CN, flags, (float*)d_out);
}

// Round 3
// 25712.967 us; speedup vs baseline: 1.6074x; 1.0772x over previous
//
#include <hip/hip_runtime.h>

#define T_   2048
#define NWG  32

typedef float  float4v __attribute__((ext_vector_type(4)));
typedef float  float2v __attribute__((ext_vector_type(2)));
typedef short  short8v __attribute__((ext_vector_type(8)));
typedef unsigned uint4v __attribute__((ext_vector_type(4)));
typedef unsigned short ushort_t;

__device__ __forceinline__ ushort_t f2bf(float f) {
  union { float f; unsigned u; } v; v.f = f;
  unsigned r = (v.u + 0x7FFFu + ((v.u >> 16) & 1u)) >> 16;  // RTN
  return (ushort_t)r;
}
__device__ __forceinline__ float sigm(float x) {
  x = fmaxf(x, -30.f);
  return __fdividef(1.f, 1.f + __expf(-x));
}
__device__ __forceinline__ float tanh_(float x) {
  x = fminf(fmaxf(x, -15.f), 15.f);
  float e = __expf(2.f * x);
  return (e - 1.f) * __fdividef(1.f, e + 1.f);
}

// W1[n,k] = sum_j W_hh[n,j] * W_hs[j,k]   (fold: h2 @ W_hh^T == h_new @ W1^T)
__global__ void k_prep_w1(const float* __restrict__ Whh, const float* __restrict__ Whs,
                          ushort_t* __restrict__ w1) {
  int idx = blockIdx.x * 256 + threadIdx.x;
  if (idx >= 2048 * 512) return;
  int n = idx >> 9, k = idx & 511;
  const float* whr = Whh + (size_t)n * 512;
  const float* wsk = Whs + k;
  float s = 0.f;
  #pragma unroll 8
  for (int j = 0; j < 512; ++j) s += whr[j] * wsk[(size_t)j * 512];
  w1[idx] = f2bf(s);
}

__global__ void k_prep_misc(const float* __restrict__ Wih, const float* __restrict__ Wcs,
                            const float* __restrict__ Whs, const float* __restrict__ bih,
                            const float* __restrict__ bhh,
                            ushort_t* __restrict__ wih_bf, ushort_t* __restrict__ wcs_bf,
                            ushort_t* __restrict__ whs_bf, float* __restrict__ bias,
                            ushort_t* __restrict__ HN, ushort_t* __restrict__ CN,
                            int* __restrict__ flags) {
  const int total = 1048576 + 262144 + 262144 + 2048 + 16384 + 16384 + 512;
  for (int i = blockIdx.x * blockDim.x + threadIdx.x; i < total; i += gridDim.x * blockDim.x) {
    int r = i;
    if (r < 1048576) { wih_bf[r] = f2bf(Wih[r]); continue; }
    r -= 1048576;
    if (r < 262144)  { wcs_bf[r] = f2bf(Wcs[r]); continue; }
    r -= 262144;
    if (r < 262144)  { whs_bf[r] = f2bf(Whs[r]); continue; }
    r -= 262144;
    if (r < 2048)    { bias[r] = bih[r] + bhh[r]; continue; }
    r -= 2048;
    if (r < 16384)   { HN[3 * 16384 + r] = 0; continue; }   // zero ring slot 3 (state t=-1)
    r -= 16384;
    if (r < 16384)   { CN[3 * 16384 + r] = 0; continue; }
    r -= 16384;
    flags[r] = 0;
  }
}

// Persistent recurrent kernel, one WG per 16-feature block (fb).
// Carry is (hn, cn); per step t:
//   gates = x_t@Wih^T + bias + hn@W1^T ; c2 = cn@Wcs^T ; h2 = hn@Whs^T
//   cn' = sig(f)*c2 + sig(i)*tanh(g) ; hn' = sig(o)*tanh(cn')
//   out[t-1] = x_{t-1} + tanh(tanh(tanh(h2+c2) + x_{t-1}))
__global__ __launch_bounds__(256, 1) void k_lstm(
    const float* __restrict__ X,
    const ushort_t* __restrict__ w1, const ushort_t* __restrict__ wih,
    const ushort_t* __restrict__ wcs, const ushort_t* __restrict__ whs,
    const float* __restrict__ bias,
    ushort_t* __restrict__ HN, ushort_t* __restrict__ CN,
    int* __restrict__ flags, float* __restrict__ out)
{
  const int fb   = blockIdx.x;
  const int tid  = threadIdx.x;
  const int wid  = tid >> 6;
  const int lane = tid & 63;
  const int mh   = wid & 1;          // batch half
  const int ar   = lane & 15;
  const int ko   = (lane >> 4) << 3;

  __shared__ float s_tiles[12][16][20];   // padded: row stride 80B -> 2-way max

  // ---- per-thread elementwise mapping + bias in registers ----
  const int eb  = tid >> 3;          // batch row 0..31
  const int ejp = (tid & 7) * 2;     // column pair within the 16-col block
  const int emh = eb >> 4, ebr = eb & 15;
  float bI[2], bF[2], bG[2], bO[2];
  #pragma unroll
  for (int u = 0; u < 2; ++u) {
    bI[u] = bias[0 * 512 + fb * 16 + ejp + u];
    bF[u] = bias[1 * 512 + fb * 16 + ejp + u];
    bG[u] = bias[2 * 512 + fb * 16 + ejp + u];
    bO[u] = bias[3 * 512 + fb * 16 + ejp + u];
  }

  const int gtype0 = wid >> 1;            // i or f
  const int gtype1 = 2 + (wid >> 1);      // g or o

  // ---- state-pass B fragments: load ONCE into registers (unified VGPR/AGPR) ----
  short8v bw0[16], bw1[16], bw2[16];
  {
    const ushort_t* p0 = w1 + ((size_t)(gtype0 * 512 + fb * 16 + ar)) * 512 + ko;
    const ushort_t* p1 = w1 + ((size_t)(gtype1 * 512 + fb * 16 + ar)) * 512 + ko;
    const ushort_t* p2 = ((wid < 2) ? wcs : whs) + ((size_t)(fb * 16 + ar)) * 512 + ko;
    #pragma unroll
    for (int kk = 0; kk < 16; ++kk) {
      bw0[kk] = *(const short8v*)(p0 + (size_t)kk * 32);
      bw1[kk] = *(const short8v*)(p1 + (size_t)kk * 32);
      bw2[kk] = *(const short8v*)(p2 + (size_t)kk * 32);
    }
  }

  const ushort_t* bx0_ = wih + ((size_t)(gtype0 * 512 + fb * 16 + ar)) * 512 + ko;
  const ushort_t* bx1_ = wih + ((size_t)(gtype1 * 512 + fb * 16 + ar)) * 512 + ko;
  const int arow_x = mh * 16 + ar;
  const int t0 = wid, t1 = wid + 4, t2 = wid + 8;

  for (int t = 0; t <= T_; ++t) {
    float4v acc0 = {0.f, 0.f, 0.f, 0.f};
    float4v acc1 = acc0, acc2 = acc0;

    // ---- prefetch output-pass X early (off the sync path) ----
    float2v xo2 = {0.f, 0.f};
    if (t > 0)
      xo2 = *(const float2v*)&X[(size_t)eb * (T_ * 512) + (size_t)(t - 1) * 512 + fb * 16 + ejp];

    // ---- x-pass (state independent, before the poll) ----
    if (t < T_) {
      const float* xrow = X + (size_t)arow_x * (T_ * 512) + (size_t)t * 512 + ko;
      const ushort_t* bx0 = bx0_;
      const ushort_t* bx1 = bx1_;
      asm volatile("" : "+v"(bx0), "+v"(bx1));   // block LICM of 256 regs of x-weights
      #pragma unroll
      for (int kk = 0; kk < 16; ++kk) {
        const float* p = xrow + kk * 32;
        float4v xa = *(const float4v*)(p);
        float4v xb = *(const float4v*)(p + 4);
        uint4v ua = __builtin_bit_cast(uint4v, xa);
        uint4v ub = __builtin_bit_cast(uint4v, xb);
        uint4v pk;
        pk[0] = __builtin_amdgcn_perm(ua[1], ua[0], 0x07060302u);
        pk[1] = __builtin_amdgcn_perm(ua[3], ua[2], 0x07060302u);
        pk[2] = __builtin_amdgcn_perm(ub[1], ub[0], 0x07060302u);
        pk[3] = __builtin_amdgcn_perm(ub[3], ub[2], 0x07060302u);
        short8v a = __builtin_bit_cast(short8v, pk);
        short8v b0 = *(const short8v*)(bx0 + (size_t)kk * 32);
        short8v b1 = *(const short8v*)(bx1 + (size_t)kk * 32);
        acc0 = __builtin_amdgcn_mfma_f32_16x16x32_bf16(a, b0, acc0, 0, 0, 0);
        acc1 = __builtin_amdgcn_mfma_f32_16x16x32_bf16(a, b1, acc1, 0, 0, 0);
      }
    }

    // ---- poll (all waves, gentle backoff), then ONE acquire fence ----
    if (t > 0) {
      while (true) {
        int v = (lane < NWG)
              ? __hip_atomic_load(flags + lane * 16, __ATOMIC_RELAXED, __HIP_MEMORY_SCOPE_AGENT)
              : t;
        if (__all(v >= t)) break;
        __builtin_amdgcn_s_sleep(1);
      }
      __builtin_amdgcn_fence(__ATOMIC_ACQUIRE, "agent");  // buffer_inv: kill stale L1/L2
    }

    // ---- state A-fragments via PLAIN pipelined dwordx4 loads ----
    const int rs = (t + 3) & 3;
    const ushort_t* hb = HN + (size_t)rs * (32 * 512) + (size_t)arow_x * 512 + ko;
    short8v hfrag[16];
    #pragma unroll
    for (int kk = 0; kk < 16; ++kk)
      hfrag[kk] = *(const short8v*)(hb + (size_t)kk * 32);
    short8v cfrag[16];
    if (wid < 2) {
      const ushort_t* cb = CN + (size_t)rs * (32 * 512) + (size_t)arow_x * 512 + ko;
      #pragma unroll
      for (int kk = 0; kk < 16; ++kk)
        cfrag[kk] = *(const short8v*)(cb + (size_t)kk * 32);
    }

    // ---- state MFMA: A from registers, B from registers ----
    #pragma unroll
    for (int kk = 0; kk < 16; ++kk) {
      acc0 = __builtin_amdgcn_mfma_f32_16x16x32_bf16(hfrag[kk], bw0[kk], acc0, 0, 0, 0);
      acc1 = __builtin_amdgcn_mfma_f32_16x16x32_bf16(hfrag[kk], bw1[kk], acc1, 0, 0, 0);
      short8v a2 = (wid < 2) ? cfrag[kk] : hfrag[kk];
      acc2 = __builtin_amdgcn_mfma_f32_16x16x32_bf16(a2, bw2[kk], acc2, 0, 0, 0);
    }

    __syncthreads();   // barrier1: prev iteration's s_tiles readers done

    {
      const int rb = (lane >> 4) << 2, cc = lane & 15;
      #pragma unroll
      for (int r = 0; r < 4; ++r) {
        s_tiles[t0][rb + r][cc] = acc0[r];
        s_tiles[t1][rb + r][cc] = acc1[r];
        s_tiles[t2][rb + r][cc] = acc2[r];
      }
    }
    __syncthreads();   // barrier2: tiles visible

    // ---- elementwise cell update + sc1 state store ----
    if (t < T_) {
      unsigned hpk = 0, cpk = 0;
      #pragma unroll
      for (int u = 0; u < 2; ++u) {
        int j = ejp + u;
        float iv  = s_tiles[0 + emh][ebr][j] + bI[u];
        float fv  = s_tiles[2 + emh][ebr][j] + bF[u];
        float gv  = s_tiles[4 + emh][ebr][j] + bG[u];
        float ov  = s_tiles[6 + emh][ebr][j] + bO[u];
        float c2p = s_tiles[8 + emh][ebr][j];
        float cnv = sigm(fv) * c2p + sigm(iv) * tanh_(gv);
        float hnv = sigm(ov) * tanh_(cnv);
        hpk |= ((unsigned)f2bf(hnv)) << (16 * u);
        cpk |= ((unsigned)f2bf(cnv)) << (16 * u);
      }
      size_t uso = (size_t)(t & 3) * (32 * 512) + (size_t)eb * 512 + fb * 16 + ejp;
      __hip_atomic_store((unsigned*)(HN + uso), hpk,
                         __ATOMIC_RELAXED, __HIP_MEMORY_SCOPE_AGENT);
      __hip_atomic_store((unsigned*)(CN + uso), cpk,
                         __ATOMIC_RELAXED, __HIP_MEMORY_SCOPE_AGENT);
    }
    __syncthreads();   // barrier3: vmcnt(0) drains the sc1 stores before the flag
    if (t < T_ && tid == 0)
      __hip_atomic_store(flags + fb * 16, t + 1, __ATOMIC_RELAXED, __HIP_MEMORY_SCOPE_AGENT);

    // ---- output for step t-1 (after signaling; uses this iteration's tiles) ----
    if (t > 0) {
      float ov2[2];
      #pragma unroll
      for (int u = 0; u < 2; ++u) {
        int j = ejp + u;
        float c2p = s_tiles[8 + emh][ebr][j];
        float h2p = s_tiles[10 + emh][ebr][j];
        float att = tanh_(h2p + c2p);
        float xo  = (u ? xo2[1] : xo2[0]);
        float o1  = tanh_(att + xo);
        ov2[u] = xo + tanh_(o1);
      }
      float2v o2; o2[0] = ov2[0]; o2[1] = ov2[1];
      *(float2v*)&out[(size_t)eb * (T_ * 512) + (size_t)(t - 1) * 512 + fb * 16 + ejp] = o2;
    }
  }
}

extern "C" void kernel_launch(void* const* d_in, const int* in_sizes, int n_in,
                              void* d_out, int out_size, void* d_ws, size_t ws_size,
                              hipStream_t stream) {
  const float* X   = (const float*)d_in[0];
  const float* Wih = (const float*)d_in[1];
  const float* Whh = (const float*)d_in[2];
  const float* bih = (const float*)d_in[3];
  const float* bhh = (const float*)d_in[4];
  const float* Whs = (const float*)d_in[5];
  const float* Wcs = (const float*)d_in[6];

  char* ws = (char*)d_ws;
  ushort_t* w1_bf  = (ushort_t*)(ws + 0);        // 2,097,152 B
  ushort_t* wih_bf = (ushort_t*)(ws + 2097152);  // 2,097,152 B
  ushort_t* wcs_bf = (ushort_t*)(ws + 4194304);  //   524,288 B
  ushort_t* whs_bf = (ushort_t*)(ws + 4718592);  //   524,288 B
  float*    bias   = (float*)   (ws + 5242880);  //     8,192 B
  ushort_t* HN     = (ushort_t*)(ws + 5251072);  //   131,072 B (4-slot ring)
  ushort_t* CN     = (ushort_t*)(ws + 5382144);  //   131,072 B
  int*      flags  = (int*)     (ws + 5513216);  //     2,048 B (64B-padded flags)
  if (ws_size < (size_t)5515264) return;

  k_prep_w1<<<4096, 256, 0, stream>>>(Whh, Whs, w1_bf);
  k_prep_misc<<<2048, 256, 0, stream>>>(Wih, Wcs, Whs, bih, bhh,
                                        wih_bf, wcs_bf, whs_bf, bias, HN, CN, flags);
  k_lstm<<<NWG, 256, 0, stream>>>(X, w1_bf, wih_bf, wcs_bf, whs_bf, bias,
                                  HN, CN, flags, (float*)d_out);
}